// Round 1
// baseline (405.210 us; speedup 1.0000x reference)
//
#include <hip/hip_runtime.h>
#include <hip/hip_bf16.h>
#include <math.h>

typedef __attribute__((ext_vector_type(8))) short short8;
typedef __attribute__((ext_vector_type(4))) short short4v;
typedef __attribute__((ext_vector_type(4))) float f32x4;

#define D 160
#define NTOK (256*512)   // 131072 rows
#define MT 64            // rows per workgroup
#define AST 328          // Acat LDS stride (bf16 elems): 160(x)+160(c)+8 pad
#define EST 168          // Eta2 LDS stride

__device__ __forceinline__ short f2bf(float f) {
  union { float f; unsigned u; } v; v.f = f;
  unsigned r = (v.u + 0x7fffu + ((v.u >> 16) & 1u)) >> 16;  // RNE
  return (short)(r & 0xffffu);
}
__device__ __forceinline__ float bf2f(short s) {
  union { float f; unsigned u; } v;
  v.u = ((unsigned)(unsigned short)s) << 16;
  return v.f;
}

// Pack weights to bf16 in workspace:
//  wcat (160 x 320): row n = [W2[n,:] | W3[n,:]]  (fused K for eta2)
//  w1b, w4b, w5b (160 x 160 each), row-major (n, k) — matches B-fragment
//  layout: lane reads 8 contiguous k at row n.
__global__ __launch_bounds__(256) void prep_kernel(
    const float* __restrict__ W2, const float* __restrict__ W3,
    const float* __restrict__ W1, const float* __restrict__ W4,
    const float* __restrict__ W5, short* __restrict__ ws) {
  int i = blockIdx.x * 256 + threadIdx.x;
  short* wcat = ws;
  short* w1b  = ws + 160 * 320;
  short* w4b  = w1b + 25600;
  short* w5b  = w4b + 25600;
  if (i < 51200) {
    int n = i / 320, k = i % 320;
    float v = (k < 160) ? W2[n * 160 + k] : W3[n * 160 + (k - 160)];
    wcat[i] = f2bf(v);
  } else if (i < 76800) {
    int j = i - 51200; w1b[j] = f2bf(W1[j]);
  } else if (i < 102400) {
    int j = i - 76800; w4b[j] = f2bf(W4[j]);
  } else if (i < 128000) {
    int j = i - 102400; w5b[j] = f2bf(W5[j]);
  }
}

// Fused GRN: eta2 = ELU([x|c] @ wcat^T + b2); eta1 = eta2 @ W1^T + b1;
// glu = sigmoid(eta1 @ W4^T + b4) * (eta1 @ W5^T + b5); y = LN(x + glu).
// 4 waves, wave w owns rows [16w, 16w+16) of the 64-row tile.
// MFMA 16x16x32 bf16. A frag: A[m=lane&15][k=(lane>>4)*8+j] (ds_read_b128).
// B frag: B[k][n], n=lane&15, k=(lane>>4)*8+j  -> 16B contiguous global load.
// C/D:   col=lane&15, row=(lane>>4)*4+reg.
__global__ __launch_bounds__(256, 2) void grn_main(
    const float* __restrict__ x, const float* __restrict__ c,
    const short* __restrict__ wcat, const short* __restrict__ w1b,
    const short* __restrict__ w4b, const short* __restrict__ w5b,
    const float* __restrict__ b2, const float* __restrict__ b1,
    const float* __restrict__ b4, const float* __restrict__ b5,
    const float* __restrict__ gamma, const float* __restrict__ beta,
    float* __restrict__ out) {
  __shared__ short Acat[MT * AST];   // cols 0:160 = x (bf16, kept for residual),
                                     // cols 160:320 = c, later overwritten by eta1
  __shared__ short Eta2[MT * EST];

  const int tid  = threadIdx.x;
  const int lane = tid & 63;
  const int wave = tid >> 6;
  const int lr   = lane & 15;
  const int quad = lane >> 4;
  const int rowbase = blockIdx.x * MT;

  // ---------------- phase 0: stage x,c -> bf16 LDS (coalesced float4) -------
  {
    const f32x4* xg = (const f32x4*)(x + (size_t)rowbase * D);
    const f32x4* cg = (const f32x4*)(c + (size_t)rowbase * D);
#pragma unroll
    for (int i = 0; i < 10; ++i) {
      int g = tid + 256 * i;          // float4 index in 64x40 tile
      int row = g / 40, col4 = g % 40;
      f32x4 vx = xg[g];
      f32x4 vc = cg[g];
      short4v sx, sc;
#pragma unroll
      for (int j = 0; j < 4; ++j) { sx[j] = f2bf(vx[j]); sc[j] = f2bf(vc[j]); }
      *(short4v*)&Acat[row * AST + col4 * 4]       = sx;
      *(short4v*)&Acat[row * AST + 160 + col4 * 4] = sc;
    }
  }
  __syncthreads();

  const int m0 = wave * 16;

  // ---------------- phase 1: eta2 = ELU(Acat(64x320) @ wcat^T + b2) ---------
  {
    f32x4 acc[10];
#pragma unroll
    for (int nt = 0; nt < 10; ++nt) acc[nt] = (f32x4){0.f, 0.f, 0.f, 0.f};
    const short* arow = &Acat[(m0 + lr) * AST + quad * 8];
    for (int ks = 0; ks < 10; ++ks) {
      short8 af = *(const short8*)(arow + ks * 32);
      const short* bp = wcat + lr * 320 + ks * 32 + quad * 8;
#pragma unroll
      for (int nt = 0; nt < 10; ++nt) {
        short8 bf = *(const short8*)(bp + nt * 16 * 320);
        acc[nt] = __builtin_amdgcn_mfma_f32_16x16x32_bf16(af, bf, acc[nt], 0, 0, 0);
      }
    }
#pragma unroll
    for (int nt = 0; nt < 10; ++nt) {
      float bias = b2[nt * 16 + lr];
#pragma unroll
      for (int r = 0; r < 4; ++r) {
        float v = acc[nt][r] + bias;
        v = v > 0.f ? v : expm1f(v);  // ELU
        Eta2[(m0 + quad * 4 + r) * EST + nt * 16 + lr] = f2bf(v);
      }
    }
  }
  __syncthreads();

  // ---------------- phase 2: eta1 = Eta2 @ W1^T + b1  -> Acat cols 160: -----
  {
    f32x4 acc[10];
#pragma unroll
    for (int nt = 0; nt < 10; ++nt) acc[nt] = (f32x4){0.f, 0.f, 0.f, 0.f};
    const short* arow = &Eta2[(m0 + lr) * EST + quad * 8];
    for (int ks = 0; ks < 5; ++ks) {
      short8 af = *(const short8*)(arow + ks * 32);
      const short* bp = w1b + lr * 160 + ks * 32 + quad * 8;
#pragma unroll
      for (int nt = 0; nt < 10; ++nt) {
        short8 bf = *(const short8*)(bp + nt * 16 * 160);
        acc[nt] = __builtin_amdgcn_mfma_f32_16x16x32_bf16(af, bf, acc[nt], 0, 0, 0);
      }
    }
#pragma unroll
    for (int nt = 0; nt < 10; ++nt) {
      float bias = b1[nt * 16 + lr];
#pragma unroll
      for (int r = 0; r < 4; ++r) {
        float v = acc[nt][r] + bias;
        Acat[(m0 + quad * 4 + r) * AST + 160 + nt * 16 + lr] = f2bf(v);
      }
    }
  }
  __syncthreads();

  // ---------------- phase 3: GLU + residual + LayerNorm ---------------------
  {
    f32x4 accg[10], accv[10];
#pragma unroll
    for (int nt = 0; nt < 10; ++nt) {
      accg[nt] = (f32x4){0.f, 0.f, 0.f, 0.f};
      accv[nt] = (f32x4){0.f, 0.f, 0.f, 0.f};
    }
    const short* arow = &Acat[(m0 + lr) * AST + 160 + quad * 8];
    for (int ks = 0; ks < 5; ++ks) {
      short8 af = *(const short8*)(arow + ks * 32);
      const short* bp4 = w4b + lr * 160 + ks * 32 + quad * 8;
      const short* bp5 = w5b + lr * 160 + ks * 32 + quad * 8;
#pragma unroll
      for (int nt = 0; nt < 10; ++nt) {
        short8 bg = *(const short8*)(bp4 + nt * 2560);
        short8 bv = *(const short8*)(bp5 + nt * 2560);
        accg[nt] = __builtin_amdgcn_mfma_f32_16x16x32_bf16(af, bg, accg[nt], 0, 0, 0);
        accv[nt] = __builtin_amdgcn_mfma_f32_16x16x32_bf16(af, bv, accv[nt], 0, 0, 0);
      }
    }

    float y[10][4];
    float sum[4] = {0.f, 0.f, 0.f, 0.f};
    float ssq[4] = {0.f, 0.f, 0.f, 0.f};
#pragma unroll
    for (int nt = 0; nt < 10; ++nt) {
      float bg = b4[nt * 16 + lr];
      float bv = b5[nt * 16 + lr];
#pragma unroll
      for (int r = 0; r < 4; ++r) {
        float g = accg[nt][r] + bg;
        float v = accv[nt][r] + bv;
        float glu = v / (1.f + __expf(-g));
        float xv = bf2f(Acat[(m0 + quad * 4 + r) * AST + nt * 16 + lr]);
        float yy = xv + glu;
        y[nt][r] = yy;
        sum[r] += yy;
        ssq[r] += yy * yy;
      }
    }
    // reduce across the 16 lanes of this quad-group (rows m0+quad*4+{0..3})
#pragma unroll
    for (int off = 1; off < 16; off <<= 1) {
#pragma unroll
      for (int r = 0; r < 4; ++r) {
        sum[r] += __shfl_xor(sum[r], off, 64);
        ssq[r] += __shfl_xor(ssq[r], off, 64);
      }
    }
    float mean[4], rstd[4];
#pragma unroll
    for (int r = 0; r < 4; ++r) {
      mean[r] = sum[r] * (1.f / 160.f);
      float var = ssq[r] * (1.f / 160.f) - mean[r] * mean[r];
      rstd[r] = rsqrtf(var + 1e-5f);
    }
#pragma unroll
    for (int nt = 0; nt < 10; ++nt) {
      int col = nt * 16 + lr;
      float ga = gamma[col];
      float be = beta[col];
#pragma unroll
      for (int r = 0; r < 4; ++r) {
        int row = rowbase + m0 + quad * 4 + r;
        out[(size_t)row * D + col] = (y[nt][r] - mean[r]) * rstd[r] * ga + be;
      }
    }
  }
}

extern "C" void kernel_launch(void* const* d_in, const int* in_sizes, int n_in,
                              void* d_out, int out_size, void* d_ws, size_t ws_size,
                              hipStream_t stream) {
  const float* x     = (const float*)d_in[0];
  const float* c     = (const float*)d_in[1];
  const float* W2    = (const float*)d_in[2];
  const float* b2    = (const float*)d_in[3];
  const float* W3    = (const float*)d_in[4];
  const float* W1    = (const float*)d_in[5];
  const float* b1    = (const float*)d_in[6];
  const float* W4    = (const float*)d_in[7];
  const float* b4    = (const float*)d_in[8];
  const float* W5    = (const float*)d_in[9];
  const float* b5    = (const float*)d_in[10];
  const float* gamma = (const float*)d_in[11];
  const float* beta  = (const float*)d_in[12];

  short* ws = (short*)d_ws;   // needs 256000 B; re-packed every launch
  prep_kernel<<<500, 256, 0, stream>>>(W2, W3, W1, W4, W5, ws);

  const short* wcat = ws;
  const short* w1b  = ws + 160 * 320;
  const short* w4b  = w1b + 25600;
  const short* w5b  = w4b + 25600;

  grn_main<<<NTOK / MT, 256, 0, stream>>>(x, c, wcat, w1b, w4b, w5b,
                                          b2, b1, b4, b5, gamma, beta,
                                          (float*)d_out);
}

// Round 2
// 344.253 us; speedup vs baseline: 1.1771x; 1.1771x over previous
//
#include <hip/hip_runtime.h>
#include <hip/hip_bf16.h>
#include <math.h>

typedef __attribute__((ext_vector_type(8))) short short8;
typedef __attribute__((ext_vector_type(4))) short short4v;
typedef __attribute__((ext_vector_type(4))) float f32x4;

#define D 160
#define NTOK (256*512)   // 131072 rows
#define MT 64            // rows per workgroup
#define AST 328          // Acat LDS stride (bf16 elems): 160(x)+160(c)+8 pad
#define EST 168          // Eta2 LDS stride

__device__ __forceinline__ short f2bf(float f) {
  union { float f; unsigned u; } v; v.f = f;
  unsigned r = (v.u + 0x7fffu + ((v.u >> 16) & 1u)) >> 16;  // RNE
  return (short)(r & 0xffffu);
}
__device__ __forceinline__ float bf2f(short s) {
  union { float f; unsigned u; } v;
  v.u = ((unsigned)(unsigned short)s) << 16;
  return v.f;
}

// Pack weights to bf16 in workspace, in MFMA B-FRAGMENT ORDER:
//   frag f = ks*10 + nt;  element (f, lane, j) = W[n][k],
//   n = nt*16 + (lane&15), k = ks*32 + (lane>>4)*8 + j.
// Kernel-side load: base + (f*64 + lane)*8 shorts -> fully coalesced 16B/lane.
//  wcatf: 100 frags (K=320: k<160 -> W2, else W3)    = 51200 shorts
//  w1f/w4f/w5f: 50 frags each (K=160)                = 25600 shorts each
__global__ __launch_bounds__(256) void prep_kernel(
    const float* __restrict__ W2, const float* __restrict__ W3,
    const float* __restrict__ W1, const float* __restrict__ W4,
    const float* __restrict__ W5, short* __restrict__ ws) {
  int i = blockIdx.x * 256 + threadIdx.x;
  if (i >= 128000) return;
  if (i < 51200) {
    int f = i >> 9, r = i & 511;
    int lane = r >> 3, j = r & 7;
    int ks = f / 10, nt = f % 10;
    int n = nt * 16 + (lane & 15);
    int k = ks * 32 + (lane >> 4) * 8 + j;
    float v = (k < 160) ? W2[n * 160 + k] : W3[n * 160 + (k - 160)];
    ws[i] = f2bf(v);
  } else {
    int idx = i - 51200;
    int which = idx / 25600;      // 0=W1, 1=W4, 2=W5
    int e = idx % 25600;
    int f = e >> 9, r = e & 511;
    int lane = r >> 3, j = r & 7;
    int ks = f / 10, nt = f % 10;
    int n = nt * 16 + (lane & 15);
    int k = ks * 32 + (lane >> 4) * 8 + j;
    const float* W = (which == 0) ? W1 : (which == 1) ? W4 : W5;
    ws[i] = f2bf(W[n * 160 + k]);
  }
}

// Fused GRN: eta2 = ELU([x|c] @ wcat^T + b2); eta1 = eta2 @ W1^T + b1;
// glu = sigmoid(eta1 @ W4^T + b4) * (eta1 @ W5^T + b5); y = LN(x + glu).
// 4 waves, wave w owns rows [16w, 16w+16) of the 64-row tile.
// MFMA 16x16x32 bf16. A frag from LDS (ds_read_b128); B frag from global in
// fragment order (coalesced). C/D: col=lane&15, row=(lane>>4)*4+reg.
__global__ __launch_bounds__(256, 2) void grn_main(
    const float* __restrict__ x, const float* __restrict__ c,
    const short* __restrict__ wcatf, const short* __restrict__ w1f,
    const short* __restrict__ w4f, const short* __restrict__ w5f,
    const float* __restrict__ b2, const float* __restrict__ b1,
    const float* __restrict__ b4, const float* __restrict__ b5,
    const float* __restrict__ gamma, const float* __restrict__ beta,
    float* __restrict__ out) {
  __shared__ short Acat[MT * AST];   // cols 0:160 = x (bf16, kept for residual),
                                     // cols 160:320 = c, later overwritten by eta1
  __shared__ short Eta2[MT * EST];

  const int tid  = threadIdx.x;
  const int lane = tid & 63;
  const int wave = tid >> 6;
  const int lr   = lane & 15;
  const int quad = lane >> 4;
  const int rowbase = blockIdx.x * MT;

  // ---------------- phase 0: stage x,c -> bf16 LDS (coalesced float4) -------
  {
    const f32x4* xg = (const f32x4*)(x + (size_t)rowbase * D);
    const f32x4* cg = (const f32x4*)(c + (size_t)rowbase * D);
#pragma unroll
    for (int i = 0; i < 10; ++i) {
      int g = tid + 256 * i;          // float4 index in 64x40 tile
      int row = g / 40, col4 = g % 40;
      f32x4 vx = xg[g];
      f32x4 vc = cg[g];
      short4v sx, sc;
#pragma unroll
      for (int j = 0; j < 4; ++j) { sx[j] = f2bf(vx[j]); sc[j] = f2bf(vc[j]); }
      *(short4v*)&Acat[row * AST + col4 * 4]       = sx;
      *(short4v*)&Acat[row * AST + 160 + col4 * 4] = sc;
    }
  }
  __syncthreads();

  const int m0 = wave * 16;

  // ---------------- phase 1: eta2 = ELU(Acat(64x320) @ wcat^T + b2) ---------
  {
    f32x4 acc[10];
#pragma unroll
    for (int nt = 0; nt < 10; ++nt) acc[nt] = (f32x4){0.f, 0.f, 0.f, 0.f};
    const short* arow = &Acat[(m0 + lr) * AST + quad * 8];
    const short* wp = wcatf + lane * 8;
    for (int ks = 0; ks < 10; ++ks) {
      short8 af = *(const short8*)(arow + ks * 32);
#pragma unroll
      for (int nt = 0; nt < 10; ++nt) {
        short8 bf = *(const short8*)(wp + ((ks * 10 + nt) << 9));
        acc[nt] = __builtin_amdgcn_mfma_f32_16x16x32_bf16(af, bf, acc[nt], 0, 0, 0);
      }
    }
#pragma unroll
    for (int nt = 0; nt < 10; ++nt) {
      float bias = b2[nt * 16 + lr];
#pragma unroll
      for (int r = 0; r < 4; ++r) {
        float v = acc[nt][r] + bias;
        v = v > 0.f ? v : expm1f(v);  // ELU
        Eta2[(m0 + quad * 4 + r) * EST + nt * 16 + lr] = f2bf(v);
      }
    }
  }
  __syncthreads();

  // ---------------- phase 2: eta1 = Eta2 @ W1^T + b1  -> Acat cols 160: -----
  {
    f32x4 acc[10];
#pragma unroll
    for (int nt = 0; nt < 10; ++nt) acc[nt] = (f32x4){0.f, 0.f, 0.f, 0.f};
    const short* arow = &Eta2[(m0 + lr) * EST + quad * 8];
    const short* wp = w1f + lane * 8;
    for (int ks = 0; ks < 5; ++ks) {
      short8 af = *(const short8*)(arow + ks * 32);
#pragma unroll
      for (int nt = 0; nt < 10; ++nt) {
        short8 bf = *(const short8*)(wp + ((ks * 10 + nt) << 9));
        acc[nt] = __builtin_amdgcn_mfma_f32_16x16x32_bf16(af, bf, acc[nt], 0, 0, 0);
      }
    }
#pragma unroll
    for (int nt = 0; nt < 10; ++nt) {
      float bias = b1[nt * 16 + lr];
#pragma unroll
      for (int r = 0; r < 4; ++r) {
        float v = acc[nt][r] + bias;
        Acat[(m0 + quad * 4 + r) * AST + 160 + nt * 16 + lr] = f2bf(v);
      }
    }
  }
  __syncthreads();

  // ---------------- phase 3: GLU + residual + LayerNorm ---------------------
  {
    f32x4 accg[10], accv[10];
#pragma unroll
    for (int nt = 0; nt < 10; ++nt) {
      accg[nt] = (f32x4){0.f, 0.f, 0.f, 0.f};
      accv[nt] = (f32x4){0.f, 0.f, 0.f, 0.f};
    }
    const short* arow = &Acat[(m0 + lr) * AST + 160 + quad * 8];
    const short* wp4 = w4f + lane * 8;
    const short* wp5 = w5f + lane * 8;
    for (int ks = 0; ks < 5; ++ks) {
      short8 af = *(const short8*)(arow + ks * 32);
#pragma unroll
      for (int nt = 0; nt < 10; ++nt) {
        short8 bg = *(const short8*)(wp4 + ((ks * 10 + nt) << 9));
        short8 bv = *(const short8*)(wp5 + ((ks * 10 + nt) << 9));
        accg[nt] = __builtin_amdgcn_mfma_f32_16x16x32_bf16(af, bg, accg[nt], 0, 0, 0);
        accv[nt] = __builtin_amdgcn_mfma_f32_16x16x32_bf16(af, bv, accv[nt], 0, 0, 0);
      }
    }

    float y[10][4];
    float sum[4] = {0.f, 0.f, 0.f, 0.f};
    float ssq[4] = {0.f, 0.f, 0.f, 0.f};
#pragma unroll
    for (int nt = 0; nt < 10; ++nt) {
      float bg = b4[nt * 16 + lr];
      float bv = b5[nt * 16 + lr];
#pragma unroll
      for (int r = 0; r < 4; ++r) {
        float g = accg[nt][r] + bg;
        float v = accv[nt][r] + bv;
        float glu = v / (1.f + __expf(-g));
        float xv = bf2f(Acat[(m0 + quad * 4 + r) * AST + nt * 16 + lr]);
        float yy = xv + glu;
        y[nt][r] = yy;
        sum[r] += yy;
        ssq[r] += yy * yy;
      }
    }
    // reduce across the 16 lanes of this quad-group (rows m0+quad*4+{0..3})
#pragma unroll
    for (int off = 1; off < 16; off <<= 1) {
#pragma unroll
      for (int r = 0; r < 4; ++r) {
        sum[r] += __shfl_xor(sum[r], off, 64);
        ssq[r] += __shfl_xor(ssq[r], off, 64);
      }
    }
    float mean[4], rstd[4];
#pragma unroll
    for (int r = 0; r < 4; ++r) {
      mean[r] = sum[r] * (1.f / 160.f);
      float var = ssq[r] * (1.f / 160.f) - mean[r] * mean[r];
      rstd[r] = rsqrtf(var + 1e-5f);
    }
#pragma unroll
    for (int nt = 0; nt < 10; ++nt) {
      int col = nt * 16 + lr;
      float ga = gamma[col];
      float be = beta[col];
#pragma unroll
      for (int r = 0; r < 4; ++r) {
        int row = rowbase + m0 + quad * 4 + r;
        out[(size_t)row * D + col] = (y[nt][r] - mean[r]) * rstd[r] * ga + be;
      }
    }
  }
}

extern "C" void kernel_launch(void* const* d_in, const int* in_sizes, int n_in,
                              void* d_out, int out_size, void* d_ws, size_t ws_size,
                              hipStream_t stream) {
  const float* x     = (const float*)d_in[0];
  const float* c     = (const float*)d_in[1];
  const float* W2    = (const float*)d_in[2];
  const float* b2    = (const float*)d_in[3];
  const float* W3    = (const float*)d_in[4];
  const float* W1    = (const float*)d_in[5];
  const float* b1    = (const float*)d_in[6];
  const float* W4    = (const float*)d_in[7];
  const float* b4    = (const float*)d_in[8];
  const float* W5    = (const float*)d_in[9];
  const float* b5    = (const float*)d_in[10];
  const float* gamma = (const float*)d_in[11];
  const float* beta  = (const float*)d_in[12];

  short* ws = (short*)d_ws;   // 256000 B; re-packed every launch
  prep_kernel<<<500, 256, 0, stream>>>(W2, W3, W1, W4, W5, ws);

  const short* wcatf = ws;
  const short* w1f   = ws + 51200;
  const short* w4f   = w1f + 25600;
  const short* w5f   = w4f + 25600;

  grn_main<<<NTOK / MT, 256, 0, stream>>>(x, c, wcatf, w1f, w4f, w5f,
                                          b2, b1, b4, b5, gamma, beta,
                                          (float*)d_out);
}

// Round 3
// 286.937 us; speedup vs baseline: 1.4122x; 1.1998x over previous
//
#include <hip/hip_runtime.h>
#include <math.h>

typedef __attribute__((ext_vector_type(8))) short short8;
typedef __attribute__((ext_vector_type(4))) short short4v;
typedef __attribute__((ext_vector_type(4))) float f32x4;

#define D 160
#define NTOK (256*512)   // 131072 rows
#define MT 64            // rows per workgroup

__device__ __forceinline__ short f2bf(float f) {
  union { float f; unsigned u; } v; v.f = f;
  return (short)((v.u + 0x8000u) >> 16);   // round-half-up (=RNE except exact ties)
}
__device__ __forceinline__ float bf2f(short s) {
  union { float f; unsigned u; } v;
  v.u = ((unsigned)(unsigned short)s) << 16;
  return v.f;
}

// LDS tile: 64 rows x 320 bf16, stride 320 (no pad, 40960 B exactly -> 4 blk/CU).
// XOR-swizzle 16B granules so 16 consecutive rows at fixed col hit distinct
// bank groups (2-way max = free). Granule index only has its low 3 bits
// permuted, and 40 granules/row is a multiple of 8 -> stays in-row.
__device__ __forceinline__ int lds_idx(int row, int col) {
  return row * 320 + ((((col >> 3) ^ (row & 7)) << 3) | (col & 7));
}

// Pack weights to bf16 in MFMA B-FRAGMENT ORDER (unchanged from R2):
//   frag f = ks*10 + nt;  element (f, lane, j) = W[n][k],
//   n = nt*16 + (lane&15), k = ks*32 + (lane>>4)*8 + j.
__global__ __launch_bounds__(256) void prep_kernel(
    const float* __restrict__ W2, const float* __restrict__ W3,
    const float* __restrict__ W1, const float* __restrict__ W4,
    const float* __restrict__ W5, short* __restrict__ ws) {
  int i = blockIdx.x * 256 + threadIdx.x;
  if (i >= 128000) return;
  if (i < 51200) {
    int f = i >> 9, r = i & 511;
    int lane = r >> 3, j = r & 7;
    int ks = f / 10, nt = f % 10;
    int n = nt * 16 + (lane & 15);
    int k = ks * 32 + (lane >> 4) * 8 + j;
    float v = (k < 160) ? W2[n * 160 + k] : W3[n * 160 + (k - 160)];
    ws[i] = f2bf(v);
  } else {
    int idx = i - 51200;
    int which = idx / 25600;      // 0=W1, 1=W4, 2=W5
    int e = idx % 25600;
    int f = e >> 9, r = e & 511;
    int lane = r >> 3, j = r & 7;
    int ks = f / 10, nt = f % 10;
    int n = nt * 16 + (lane & 15);
    int k = ks * 32 + (lane >> 4) * 8 + j;
    const float* W = (which == 0) ? W1 : (which == 1) ? W4 : W5;
    ws[i] = f2bf(W[n * 160 + k]);
  }
}

// Fused GRN. 4 waves / block; wave w owns rows [16w,16w+16).
// After the single post-staging barrier, every LDS access is wave-local rows:
//   phase1 reads [x|c] (cols 0:320), writes eta2 over x (cols 0:160)
//   phase2 reads eta2, writes eta1 over c (cols 160:320)
//   phase3 reads eta1; residual x is re-read from global (L2/L3-warm).
__global__ __launch_bounds__(256, 3) void grn_main(
    const float* __restrict__ x, const float* __restrict__ c,
    const short* __restrict__ wcatf, const short* __restrict__ w1f,
    const short* __restrict__ w4f, const short* __restrict__ w5f,
    const float* __restrict__ b2, const float* __restrict__ b1,
    const float* __restrict__ b4, const float* __restrict__ b5,
    const float* __restrict__ gamma, const float* __restrict__ beta,
    float* __restrict__ out) {
  __shared__ __align__(16) short Acat[MT * 320];   // 40960 B

  const int tid  = threadIdx.x;
  const int lane = tid & 63;
  const int wave = tid >> 6;
  const int lr   = lane & 15;
  const int quad = lane >> 4;
  const int rowbase = blockIdx.x * MT;
  const int m0 = wave * 16;

  // ---------------- phase 0: stage x,c -> bf16 LDS (coalesced float4) -------
  {
    const f32x4* xg = (const f32x4*)(x + (size_t)rowbase * D);
    const f32x4* cg = (const f32x4*)(c + (size_t)rowbase * D);
#pragma unroll
    for (int i = 0; i < 10; ++i) {
      int g = tid + 256 * i;          // float4 index in 64x40 tile
      int row = g / 40, col4 = g - row * 40;
      f32x4 vx = xg[g];
      f32x4 vc = cg[g];
      short4v sx, sc;
#pragma unroll
      for (int j = 0; j < 4; ++j) { sx[j] = f2bf(vx[j]); sc[j] = f2bf(vc[j]); }
      *(short4v*)&Acat[lds_idx(row, col4 * 4)]       = sx;   // 8B-aligned
      *(short4v*)&Acat[lds_idx(row, 160 + col4 * 4)] = sc;
    }
  }
  __syncthreads();   // the only barrier

  // ---------------- phase 1: eta2 = ELU([x|c] @ wcat^T + b2) ----------------
  {
    f32x4 acc[10];
#pragma unroll
    for (int nt = 0; nt < 10; ++nt) acc[nt] = (f32x4){0.f, 0.f, 0.f, 0.f};
    const short* wp = wcatf + lane * 8;
    short8 bf[10], bn[10];
#pragma unroll
    for (int nt = 0; nt < 10; ++nt) bf[nt] = *(const short8*)(wp + (nt << 9));
#pragma unroll
    for (int ks = 0; ks < 10; ++ks) {
      short8 af = *(const short8*)&Acat[lds_idx(m0 + lr, ks * 32 + quad * 8)];
#pragma unroll
      for (int nt = 0; nt < 10; ++nt)
        if (ks < 9) bn[nt] = *(const short8*)(wp + (((ks + 1) * 10 + nt) << 9));
#pragma unroll
      for (int nt = 0; nt < 10; ++nt)
        acc[nt] = __builtin_amdgcn_mfma_f32_16x16x32_bf16(af, bf[nt], acc[nt], 0, 0, 0);
#pragma unroll
      for (int nt = 0; nt < 10; ++nt)
        if (ks < 9) bf[nt] = bn[nt];
    }
#pragma unroll
    for (int nt = 0; nt < 10; ++nt) {
      float bias = b2[nt * 16 + lr];
#pragma unroll
      for (int r = 0; r < 4; ++r) {
        float v = acc[nt][r] + bias;
        v = v > 0.f ? v : (__expf(v) - 1.f);   // ELU
        Acat[lds_idx(m0 + quad * 4 + r, nt * 16 + lr)] = f2bf(v);
      }
    }
  }

  // ---------------- phase 2: eta1 = eta2 @ W1^T + b1 -> cols 160:320 --------
  {
    f32x4 acc[10];
#pragma unroll
    for (int nt = 0; nt < 10; ++nt) acc[nt] = (f32x4){0.f, 0.f, 0.f, 0.f};
    const short* wp = w1f + lane * 8;
    short8 bf[10], bn[10];
#pragma unroll
    for (int nt = 0; nt < 10; ++nt) bf[nt] = *(const short8*)(wp + (nt << 9));
#pragma unroll
    for (int ks = 0; ks < 5; ++ks) {
      short8 af = *(const short8*)&Acat[lds_idx(m0 + lr, ks * 32 + quad * 8)];
#pragma unroll
      for (int nt = 0; nt < 10; ++nt)
        if (ks < 4) bn[nt] = *(const short8*)(wp + (((ks + 1) * 10 + nt) << 9));
#pragma unroll
      for (int nt = 0; nt < 10; ++nt)
        acc[nt] = __builtin_amdgcn_mfma_f32_16x16x32_bf16(af, bf[nt], acc[nt], 0, 0, 0);
#pragma unroll
      for (int nt = 0; nt < 10; ++nt)
        if (ks < 4) bf[nt] = bn[nt];
    }
#pragma unroll
    for (int nt = 0; nt < 10; ++nt) {
      float bias = b1[nt * 16 + lr];
#pragma unroll
      for (int r = 0; r < 4; ++r) {
        float v = acc[nt][r] + bias;
        Acat[lds_idx(m0 + quad * 4 + r, 160 + nt * 16 + lr)] = f2bf(v);
      }
    }
  }

  // ---------------- phase 3: GLU + residual + LayerNorm ---------------------
  {
    f32x4 accg[10], accv[10];
#pragma unroll
    for (int nt = 0; nt < 10; ++nt) {
      accg[nt] = (f32x4){0.f, 0.f, 0.f, 0.f};
      accv[nt] = (f32x4){0.f, 0.f, 0.f, 0.f};
    }
    const short* wp4 = w4f + lane * 8;
    const short* wp5 = w5f + lane * 8;
#pragma unroll
    for (int ks = 0; ks < 5; ++ks) {
      short8 af = *(const short8*)&Acat[lds_idx(m0 + lr, 160 + ks * 32 + quad * 8)];
      short8 bg[10], bv[10];
#pragma unroll
      for (int nt = 0; nt < 10; ++nt) {
        bg[nt] = *(const short8*)(wp4 + (((ks * 10 + nt)) << 9));
        bv[nt] = *(const short8*)(wp5 + (((ks * 10 + nt)) << 9));
      }
#pragma unroll
      for (int nt = 0; nt < 10; ++nt) {
        accg[nt] = __builtin_amdgcn_mfma_f32_16x16x32_bf16(af, bg[nt], accg[nt], 0, 0, 0);
        accv[nt] = __builtin_amdgcn_mfma_f32_16x16x32_bf16(af, bv[nt], accv[nt], 0, 0, 0);
      }
    }

    // residual x reload at C/D positions (64B contiguous per quad-row; L2-warm)
    float xr[10][4];
#pragma unroll
    for (int nt = 0; nt < 10; ++nt)
#pragma unroll
      for (int r = 0; r < 4; ++r)
        xr[nt][r] = x[(size_t)(rowbase + m0 + quad * 4 + r) * D + nt * 16 + lr];

    float y[10][4];
    float sum[4] = {0.f, 0.f, 0.f, 0.f};
    float ssq[4] = {0.f, 0.f, 0.f, 0.f};
#pragma unroll
    for (int nt = 0; nt < 10; ++nt) {
      float bgs = b4[nt * 16 + lr];
      float bvs = b5[nt * 16 + lr];
#pragma unroll
      for (int r = 0; r < 4; ++r) {
        float g = accg[nt][r] + bgs;
        float v = accv[nt][r] + bvs;
        float glu = v * __builtin_amdgcn_rcpf(1.f + __expf(-g));
        float yy = xr[nt][r] + glu;
        y[nt][r] = yy;
        sum[r] += yy;
        ssq[r] += yy * yy;
      }
    }
    // reduce across the 16 lanes of this quad-group (rows m0+quad*4+{0..3})
#pragma unroll
    for (int off = 1; off < 16; off <<= 1) {
#pragma unroll
      for (int r = 0; r < 4; ++r) {
        sum[r] += __shfl_xor(sum[r], off, 64);
        ssq[r] += __shfl_xor(ssq[r], off, 64);
      }
    }
    float mean[4], rstd[4];
#pragma unroll
    for (int r = 0; r < 4; ++r) {
      mean[r] = sum[r] * (1.f / 160.f);
      float var = ssq[r] * (1.f / 160.f) - mean[r] * mean[r];
      rstd[r] = __builtin_amdgcn_rsqf(var + 1e-5f);
    }
#pragma unroll
    for (int nt = 0; nt < 10; ++nt) {
      int col = nt * 16 + lr;
      float ga = gamma[col];
      float be = beta[col];
#pragma unroll
      for (int r = 0; r < 4; ++r) {
        int row = rowbase + m0 + quad * 4 + r;
        out[(size_t)row * D + col] = (y[nt][r] - mean[r]) * rstd[r] * ga + be;
      }
    }
  }
}

extern "C" void kernel_launch(void* const* d_in, const int* in_sizes, int n_in,
                              void* d_out, int out_size, void* d_ws, size_t ws_size,
                              hipStream_t stream) {
  const float* x     = (const float*)d_in[0];
  const float* c     = (const float*)d_in[1];
  const float* W2    = (const float*)d_in[2];
  const float* b2    = (const float*)d_in[3];
  const float* W3    = (const float*)d_in[4];
  const float* W1    = (const float*)d_in[5];
  const float* b1    = (const float*)d_in[6];
  const float* W4    = (const float*)d_in[7];
  const float* b4    = (const float*)d_in[8];
  const float* W5    = (const float*)d_in[9];
  const float* b5    = (const float*)d_in[10];
  const float* gamma = (const float*)d_in[11];
  const float* beta  = (const float*)d_in[12];

  short* ws = (short*)d_ws;   // 256000 B; re-packed every launch
  prep_kernel<<<500, 256, 0, stream>>>(W2, W3, W1, W4, W5, ws);

  const short* wcatf = ws;
  const short* w1f   = ws + 51200;
  const short* w4f   = w1f + 25600;
  const short* w5f   = w4f + 25600;

  grn_main<<<NTOK / MT, 256, 0, stream>>>(x, c, wcatf, w1f, w4f, w5f,
                                          b2, b1, b4, b5, gamma, beta,
                                          (float*)d_out);
}